// Round 8
// baseline (526.831 us; speedup 1.0000x reference)
//
#include <hip/hip_runtime.h>
#include <math.h>

// Problem constants (fixed by the reference).
#define NU   100000      // N users
#define MI   50000       // M items
#define NEn  150000      // NE = N + M
#define Bp   131072      // batch pairs

#define PB   256         // partial-sum blocks in K2 (two pairs per thread)
#define NSLOT 8          // hdr accumulator slots (atomics spread)

// Native vector types (__builtin_nontemporal_* rejects struct float4).
typedef float    f4v __attribute__((ext_vector_type(4)));
typedef _Float16 h8v __attribute__((ext_vector_type(8)));   // 16 B of fp16
typedef _Float16 h4v __attribute__((ext_vector_type(4)));   // 8 B of fp16

// ---------------------------------------------------------------------------
// 64-lane wave reduction (gfx950 wave = 64).
__device__ __forceinline__ float wred(float v) {
#pragma unroll
    for (int m = 32; m > 0; m >>= 1) v += __shfl_xor(v, m, 64);
    return v;
}
// 32-lane (half-wave) reduction: xor masks 16..1 stay within each half.
__device__ __forceinline__ float hred(float v) {
#pragma unroll
    for (int m = 16; m > 0; m >>= 1) v += __shfl_xor(v, m, 64);
    return v;
}

// ---------------------------------------------------------------------------
// K1: entity reparam + per-row KL. One-shot: NEn/4 blocks, one wave per row
// (R4/R7-verified geometry). No histogram, no memset: cnt is algebraically
// eliminated (see K2 partials). Block 0 zeroes hdr+done and seeds kl_global.
// Streaming inputs nontemporal; fp16 enth output left cache-resident for K2.
__global__ __launch_bounds__(256) void k_ent(
    const f4v* __restrict__ et,       // entity_table, NE x 2D (row = 128 f4v)
    const f4v* __restrict__ epse,     // eps_entity,   NE x D  (row = 64 f4v)
    const float* __restrict__ bt,     // bias_table,   NE x 2
    const float* __restrict__ epsb,   // eps_bias,     NE
    const float* __restrict__ gbm,
    const float* __restrict__ gbs,
    h4v*   __restrict__ enth,         // out: entities_all fp16 (512 B rows); may be null
    float* __restrict__ bia,          // out: biases_all
    float* __restrict__ klpe,         // out: kl_bias + kl_entity per row
    float* __restrict__ hdr,          // zeroed here: NSLOT x {U,I,A,B} + done ctr
    float* __restrict__ outkl)        // out[Bp] seeded with kl_global
{
    if (blockIdx.x == 0) {
        if (threadIdx.x < 64) hdr[threadIdx.x] = 0.f;   // hdr slots + done ctr
        if (threadIdx.x == 0) {
            float gm = gbm[0], gs = fabsf(gbs[0]);
            outkl[0] = 0.5f * (gs * gs + gm * gm - 1.0f) - __logf(gs);
        }
    }

    int lane = threadIdx.x & 63;
    int e    = blockIdx.x * 4 + (threadIdx.x >> 6);

    const f4v* row = et + (size_t)e * 128;
    f4v mu = __builtin_nontemporal_load(row + lane);
    f4v s4 = __builtin_nontemporal_load(row + 64 + lane);
    f4v ep = __builtin_nontemporal_load(epse + (size_t)e * 64 + lane);
    float scx = fabsf(s4.x), scy = fabsf(s4.y), scz = fabsf(s4.z), scw = fabsf(s4.w);

    if (enth) {
        h4v oh;
        oh.x = (_Float16)fmaf(scx, ep.x, mu.x);
        oh.y = (_Float16)fmaf(scy, ep.y, mu.y);
        oh.z = (_Float16)fmaf(scz, ep.z, mu.z);
        oh.w = (_Float16)fmaf(scw, ep.w, mu.w);
        enth[(size_t)e * 64 + lane] = oh;   // temporal: want this cache-resident
    }

    float kl = 0.5f * (scx * scx + mu.x * mu.x - 1.0f) - __logf(scx)
             + 0.5f * (scy * scy + mu.y * mu.y - 1.0f) - __logf(scy)
             + 0.5f * (scz * scz + mu.z * mu.z - 1.0f) - __logf(scz)
             + 0.5f * (scw * scw + mu.w * mu.w - 1.0f) - __logf(scw);
    kl = wred(kl);

    if (lane == 0) {
        float bmu = bt[2 * e];
        float bsc = fabsf(bt[2 * e + 1]);
        bia[e]  = fmaf(bsc, epsb[e], bmu);
        klpe[e] = kl + 0.5f * (bsc * bsc + bmu * bmu - 1.0f) - __logf(bsc);
    }
}

// ---------------------------------------------------------------------------
// K2: KL partial sums over the BATCH (blocks [0,PB), TWO pairs per thread)
// CONCURRENT with logits (blocks [PB, PB+Bp/8), fp16 gather, 2 pairs per
// wave / 16 B per lane — exact R4/R7-verified logits shape, no added work).
//
// cnt-free algebra (verified R5-R7): per pair (u,v), u in [0,N), v in [N,NE):
//   U += 1/nb[u];  I += 1/nb[v]
//   A += klpe[u]/nb[u] + (v==NU ? klpe[v]/nb[v] : 0)   (ids<=N quirk: e=N)
//   B += (v>NU  ? klpe[v]/nb[v] : 0)
// kl_rescaled = N*A/U + M*B/I. FINALIZE IS FOLDED IN (no k_fin dispatch):
// each partial block, after its hdr atomics are complete (__syncthreads
// drains vmcnt -> atomics done), fences and bumps a done-counter; the last
// block re-reads hdr through atomicAdd(p,0) (coherent path, G16) and adds
// the result onto out[Bp].
__global__ __launch_bounds__(256) void k_log(
    const int2* __restrict__ x2,
    const h8v* __restrict__ enth,     // row = 32 h8v (512 B); may be null
    const float* __restrict__ bia,
    const float* __restrict__ klpe,
    const int* __restrict__ nb,
    const float* __restrict__ gbm, const float* __restrict__ gbs,
    const float* __restrict__ epsg,
    float* __restrict__ hdr,          // NSLOT x {U,I,A,B}; done ctr at hdr[4*NSLOT]
    float* __restrict__ out)
{
    if (blockIdx.x < PB) {
        // ---- partials part: two pairs per thread, coalesced int4 read ----
        int t = blockIdx.x * 256 + threadIdx.x;       // PB*256*2 == Bp exactly
        int4 pr = ((const int4*)x2)[t];               // pairs 2t, 2t+1
        float rn0 = 1.0f / (float)nb[pr.x];
        float rn1 = 1.0f / (float)nb[pr.y];
        float rn2 = 1.0f / (float)nb[pr.z];
        float rn3 = 1.0f / (float)nb[pr.w];
        float a0  = klpe[pr.x] * rn0;
        float a1  = klpe[pr.y] * rn1;
        float a2  = klpe[pr.z] * rn2;
        float a3  = klpe[pr.w] * rn3;
        float uS = rn0 + rn2;
        float iS = rn1 + rn3;
        float aS = a0 + a2 + ((pr.y == NU) ? a1 : 0.f) + ((pr.w == NU) ? a3 : 0.f);
        float bS = ((pr.y > NU) ? a1 : 0.f) + ((pr.w > NU) ? a3 : 0.f);

        uS = wred(uS); iS = wred(iS); aS = wred(aS); bS = wred(bS);
        __shared__ float s[4][4];
        int wib = threadIdx.x >> 6;
        if ((threadIdx.x & 63) == 0) {
            s[wib][0] = uS; s[wib][1] = iS; s[wib][2] = aS; s[wib][3] = bS;
        }
        __syncthreads();
        if (threadIdx.x < 4) {
            float v = s[0][threadIdx.x] + s[1][threadIdx.x]
                    + s[2][threadIdx.x] + s[3][threadIdx.x];
            atomicAdd(hdr + (blockIdx.x & (NSLOT - 1)) * 4 + threadIdx.x, v);
        }
        __syncthreads();                              // hdr atomics complete
        if (threadIdx.x == 0) {
            __threadfence();                          // order before done-inc
            unsigned old = atomicAdd((unsigned*)(hdr + 4 * NSLOT), 1u);
            if (old == PB - 1) {
                // last partial block: fold slots + finalize KL scalar
                float U = 0.f, I = 0.f, A = 0.f, Bv = 0.f;
#pragma unroll
                for (int i = 0; i < NSLOT; ++i) {
                    U  += atomicAdd(hdr + i * 4 + 0, 0.f);
                    I  += atomicAdd(hdr + i * 4 + 1, 0.f);
                    A  += atomicAdd(hdr + i * 4 + 2, 0.f);
                    Bv += atomicAdd(hdr + i * 4 + 3, 0.f);
                }
                // out[Bp] holds kl_global (written in K1; visible across the
                // dispatch boundary); single writer here.
                out[Bp] += (float)NU * A / U + (float)MI * Bv / I;
            }
        }
        return;
    }

    // ---- logits part (exact R4/R7-verified shape) ----
    int lane = threadIdx.x & 63;
    int sub  = lane & 31;                      // lane within half-wave
    int p    = (blockIdx.x - PB) * 8 + ((threadIdx.x >> 6) << 1) + (lane >> 5);
    int2 pr = x2[p];
    int u = pr.x, v = pr.y;
    float bu = bia[u];                         // prefetch: overlaps the gathers
    float bv = bia[v];
    h8v a = enth[(size_t)u * 32 + sub];
    h8v b = enth[(size_t)v * 32 + sub];
    float d = 0.f;
#pragma unroll
    for (int i = 0; i < 8; ++i) d = fmaf((float)a[i], (float)b[i], d);
    d = hred(d);
    if (sub == 0) {
        float gb = fmaf(fabsf(gbs[0]), epsg[0], gbm[0]);
        __builtin_nontemporal_store(gb + bu + bv + d, out + p);
    }
}

// ---------------------------------------------------------------------------
// Fallback gather (ws too small for fp16 ent — never expected, ws ~1.2 GB):
// recompute reparameterized rows in the gather, one pair per wave.
__global__ __launch_bounds__(256) void k_logits_rc(
    const int* __restrict__ x, const float4* __restrict__ et,
    const float4* __restrict__ epse, const float* __restrict__ bia,
    const float* __restrict__ gbm, const float* __restrict__ gbs,
    const float* __restrict__ epsg, float* __restrict__ out)
{
    int lane = threadIdx.x & 63;
    int p    = blockIdx.x * 4 + (threadIdx.x >> 6);
    int u = x[2 * p], v = x[2 * p + 1];
    const float4* ru = et + (size_t)u * 128;
    const float4* rv = et + (size_t)v * 128;
    float4 mu_u = ru[lane], s_u = ru[64 + lane], e_u = epse[(size_t)u * 64 + lane];
    float4 mu_v = rv[lane], s_v = rv[64 + lane], e_v = epse[(size_t)v * 64 + lane];
    float ax = fmaf(fabsf(s_u.x), e_u.x, mu_u.x), bx = fmaf(fabsf(s_v.x), e_v.x, mu_v.x);
    float ay = fmaf(fabsf(s_u.y), e_u.y, mu_u.y), by = fmaf(fabsf(s_v.y), e_v.y, mu_v.y);
    float az = fmaf(fabsf(s_u.z), e_u.z, mu_u.z), bz = fmaf(fabsf(s_v.z), e_v.z, mu_v.z);
    float aw = fmaf(fabsf(s_u.w), e_u.w, mu_u.w), bw = fmaf(fabsf(s_v.w), e_v.w, mu_v.w);
    float d = ax * bx + ay * by + az * bz + aw * bw;
    d = wred(d);
    if (lane == 0) {
        float gb = fmaf(fabsf(gbs[0]), epsg[0], gbm[0]);
        out[p] = gb + bia[u] + bia[v] + d;
    }
}

// ---------------------------------------------------------------------------
extern "C" void kernel_launch(void* const* d_in, const int* in_sizes, int n_in,
                              void* d_out, int out_size, void* d_ws, size_t ws_size,
                              hipStream_t stream)
{
    const int*   x    = (const int*)d_in[0];
    const float* bt   = (const float*)d_in[1];
    const float* et   = (const float*)d_in[2];
    const float* gbm  = (const float*)d_in[3];
    const float* gbs  = (const float*)d_in[4];
    const int*   nb   = (const int*)d_in[5];
    const float* epsb = (const float*)d_in[6];
    const float* epse = (const float*)d_in[7];
    const float* epsg = (const float*)d_in[8];
    float* out = (float*)d_out;   // [0..Bp) logits, [Bp] KL scalar

    char*  ws   = (char*)d_ws;
    float* hdr  = (float*)ws;                              // NSLOT x {U,I,A,B} + done
    float* klpe = (float*)(ws + 512);                      // NE floats
    float* bia  = (float*)(ws + 512 + (size_t)NEn * 4);    // NE floats
    size_t entoff = 512 + (size_t)NEn * 8;                 // 16B-aligned
    h4v* enth = nullptr;
    if (ws_size >= entoff + (size_t)NEn * 512)             // fp16 rows: 512 B each
        enth = (h4v*)(ws + entoff);

    // No memset: hdr+done zeroed inside k_ent (block 0); cnt eliminated.

    // K1: entity reparam + KL, one-shot, one wave per row.
    k_ent<<<NEn / 4, 256, 0, stream>>>(
        (const f4v*)et, (const f4v*)epse, bt, epsb,
        gbm, gbs, enth, bia, klpe, hdr, out + Bp);

    // K2: batch partials + folded finalize (PB blocks) || logits (Bp/8).
    if (enth) {
        k_log<<<PB + Bp / 8, 256, 0, stream>>>(
            (const int2*)x, (const h8v*)enth, bia, klpe, nb,
            gbm, gbs, epsg, hdr, out);
    } else {
        k_log<<<PB, 256, 0, stream>>>(         // partials+finalize only
            (const int2*)x, nullptr, bia, klpe, nb,
            gbm, gbs, epsg, hdr, out);
        k_logits_rc<<<Bp / 4, 256, 0, stream>>>(x, (const float4*)et,
                                                (const float4*)epse, bia,
                                                gbm, gbs, epsg, out);
    }
}

// Round 9
// 518.715 us; speedup vs baseline: 1.0156x; 1.0156x over previous
//
#include <hip/hip_runtime.h>
#include <math.h>

// Problem constants (fixed by the reference).
#define NU   100000      // N users
#define MI   50000       // M items
#define NEn  150000      // NE = N + M
#define Bp   131072      // batch pairs

#define PB   512         // partial-sum blocks in K2 (one pair per thread)
#define NSLOT 8          // hdr accumulator slots (atomics spread)

// Native vector types (__builtin_nontemporal_* rejects struct float4).
typedef float    f4v __attribute__((ext_vector_type(4)));
typedef _Float16 h8v __attribute__((ext_vector_type(8)));   // 16 B of fp16
typedef _Float16 h4v __attribute__((ext_vector_type(4)));   // 8 B of fp16

// ---------------------------------------------------------------------------
// 64-lane wave reduction (gfx950 wave = 64).
__device__ __forceinline__ float wred(float v) {
#pragma unroll
    for (int m = 32; m > 0; m >>= 1) v += __shfl_xor(v, m, 64);
    return v;
}
// 32-lane (half-wave) reduction: xor masks 16..1 stay within each half.
__device__ __forceinline__ float hred(float v) {
#pragma unroll
    for (int m = 16; m > 0; m >>= 1) v += __shfl_xor(v, m, 64);
    return v;
}

// ---------------------------------------------------------------------------
// K1: entity reparam + per-row KL. One-shot: NEn/4 blocks, one wave per row
// (R4/R7-verified geometry). No histogram, no memset: cnt is algebraically
// eliminated (see K2 partials). Block 0 zeroes hdr slots + seeds kl_global.
// Streaming inputs nontemporal; fp16 enth output left cache-resident for K2.
__global__ __launch_bounds__(256) void k_ent(
    const f4v* __restrict__ et,       // entity_table, NE x 2D (row = 128 f4v)
    const f4v* __restrict__ epse,     // eps_entity,   NE x D  (row = 64 f4v)
    const float* __restrict__ bt,     // bias_table,   NE x 2
    const float* __restrict__ epsb,   // eps_bias,     NE
    const float* __restrict__ gbm,
    const float* __restrict__ gbs,
    h4v*   __restrict__ enth,         // out: entities_all fp16 (512 B rows); may be null
    float* __restrict__ bia,          // out: biases_all
    float* __restrict__ klpe,         // out: kl_bias + kl_entity per row
    float* __restrict__ hdr,          // zeroed here: NSLOT slots x {U,I,A,B}
    float* __restrict__ outkl)        // out[Bp] seeded with kl_global
{
    if (blockIdx.x == 0) {
        if (threadIdx.x < 4 * NSLOT) hdr[threadIdx.x] = 0.f;
        if (threadIdx.x == 0) {
            float gm = gbm[0], gs = fabsf(gbs[0]);
            outkl[0] = 0.5f * (gs * gs + gm * gm - 1.0f) - __logf(gs);
        }
    }

    int lane = threadIdx.x & 63;
    int e    = blockIdx.x * 4 + (threadIdx.x >> 6);

    const f4v* row = et + (size_t)e * 128;
    f4v mu = __builtin_nontemporal_load(row + lane);
    f4v s4 = __builtin_nontemporal_load(row + 64 + lane);
    f4v ep = __builtin_nontemporal_load(epse + (size_t)e * 64 + lane);
    float scx = fabsf(s4.x), scy = fabsf(s4.y), scz = fabsf(s4.z), scw = fabsf(s4.w);

    if (enth) {
        h4v oh;
        oh.x = (_Float16)fmaf(scx, ep.x, mu.x);
        oh.y = (_Float16)fmaf(scy, ep.y, mu.y);
        oh.z = (_Float16)fmaf(scz, ep.z, mu.z);
        oh.w = (_Float16)fmaf(scw, ep.w, mu.w);
        enth[(size_t)e * 64 + lane] = oh;   // temporal: want this cache-resident
    }

    float kl = 0.5f * (scx * scx + mu.x * mu.x - 1.0f) - __logf(scx)
             + 0.5f * (scy * scy + mu.y * mu.y - 1.0f) - __logf(scy)
             + 0.5f * (scz * scz + mu.z * mu.z - 1.0f) - __logf(scz)
             + 0.5f * (scw * scw + mu.w * mu.w - 1.0f) - __logf(scw);
    kl = wred(kl);

    if (lane == 0) {
        float bmu = bt[2 * e];
        float bsc = fabsf(bt[2 * e + 1]);
        bia[e]  = fmaf(bsc, epsb[e], bmu);
        klpe[e] = kl + 0.5f * (bsc * bsc + bmu * bmu - 1.0f) - __logf(bsc);
    }
}

// ---------------------------------------------------------------------------
// K2: KL partial sums over the BATCH (blocks [0,PB), one pair per thread)
// CONCURRENT with logits (blocks [PB, PB+Bp/8), fp16 gather, 2 pairs per
// wave / 16 B per lane — exact R4-verified logits shape, no added work).
//
// cnt-free algebra (verified R5-R7): per pair (u,v), u in [0,N), v in [N,NE):
//   U += 1/nb[u];  I += 1/nb[v]
//   A += klpe[u]/nb[u] + (v==NU ? klpe[v]/nb[v] : 0)   (ids<=N quirk: e=N)
//   B += (v>NU  ? klpe[v]/nb[v] : 0)
// kl_rescaled = N*A/U + M*B/I (finalized by K3). Partial blocks: 4 wave-
// reductions -> LDS -> 4 atomics/block spread over NSLOT hdr slots.
__global__ __launch_bounds__(256) void k_log(
    const int2* __restrict__ x2,
    const h8v* __restrict__ enth,     // row = 32 h8v (512 B); may be null
    const float* __restrict__ bia,
    const float* __restrict__ klpe,
    const int* __restrict__ nb,
    const float* __restrict__ gbm, const float* __restrict__ gbs,
    const float* __restrict__ epsg,
    float* __restrict__ hdr,
    float* __restrict__ out)
{
    if (blockIdx.x < PB) {
        // ---- partials part: one pair per thread, coalesced x2 read ----
        int p = blockIdx.x * 256 + threadIdx.x;       // PB*256 == Bp exactly
        int2 pr = x2[p];
        int u = pr.x, v = pr.y;
        float rnu = 1.0f / (float)nb[u];
        float rnv = 1.0f / (float)nb[v];
        float au  = klpe[u] * rnu;
        float av  = klpe[v] * rnv;
        float uS = rnu;
        float iS = rnv;
        float aS = au + ((v == NU) ? av : 0.f);
        float bS = ((v > NU) ? av : 0.f);

        uS = wred(uS); iS = wred(iS); aS = wred(aS); bS = wred(bS);
        __shared__ float s[4][4];
        int wib = threadIdx.x >> 6;
        if ((threadIdx.x & 63) == 0) {
            s[wib][0] = uS; s[wib][1] = iS; s[wib][2] = aS; s[wib][3] = bS;
        }
        __syncthreads();
        if (threadIdx.x < 4) {
            float t = s[0][threadIdx.x] + s[1][threadIdx.x]
                    + s[2][threadIdx.x] + s[3][threadIdx.x];
            atomicAdd(hdr + (blockIdx.x & (NSLOT - 1)) * 4 + threadIdx.x, t);
        }
        return;
    }

    // ---- logits part (exact R4-verified shape) ----
    int lane = threadIdx.x & 63;
    int sub  = lane & 31;                      // lane within half-wave
    int p    = (blockIdx.x - PB) * 8 + ((threadIdx.x >> 6) << 1) + (lane >> 5);
    int2 pr = x2[p];
    int u = pr.x, v = pr.y;
    float bu = bia[u];                         // prefetch: overlaps the gathers
    float bv = bia[v];
    h8v a = enth[(size_t)u * 32 + sub];
    h8v b = enth[(size_t)v * 32 + sub];
    float d = 0.f;
#pragma unroll
    for (int i = 0; i < 8; ++i) d = fmaf((float)a[i], (float)b[i], d);
    d = hred(d);
    if (sub == 0) {
        float gb = fmaf(fabsf(gbs[0]), epsg[0], gbm[0]);
        __builtin_nontemporal_store(gb + bu + bv + d, out + p);
    }
}

// ---------------------------------------------------------------------------
// K3: finalize KL scalar. out[Bp] already holds kl_global (K1).
// hdr = NSLOT slots of {U, I, A, B};  kl_rescaled = N*A/U + M*B/I.
__global__ void k_fin(const float* __restrict__ hdr, float* __restrict__ outkl) {
    if (threadIdx.x == 0) {
        float U = 0.f, I = 0.f, A = 0.f, Bv = 0.f;
#pragma unroll
        for (int i = 0; i < NSLOT; ++i) {
            U  += hdr[i * 4 + 0];
            I  += hdr[i * 4 + 1];
            A  += hdr[i * 4 + 2];
            Bv += hdr[i * 4 + 3];
        }
        outkl[0] += (float)NU * A / U + (float)MI * Bv / I;
    }
}

// ---------------------------------------------------------------------------
// Fallback gather (ws too small for fp16 ent — never expected, ws ~1.2 GB):
// recompute reparameterized rows in the gather, one pair per wave.
__global__ __launch_bounds__(256) void k_logits_rc(
    const int* __restrict__ x, const float4* __restrict__ et,
    const float4* __restrict__ epse, const float* __restrict__ bia,
    const float* __restrict__ gbm, const float* __restrict__ gbs,
    const float* __restrict__ epsg, float* __restrict__ out)
{
    int lane = threadIdx.x & 63;
    int p    = blockIdx.x * 4 + (threadIdx.x >> 6);
    int u = x[2 * p], v = x[2 * p + 1];
    const float4* ru = et + (size_t)u * 128;
    const float4* rv = et + (size_t)v * 128;
    float4 mu_u = ru[lane], s_u = ru[64 + lane], e_u = epse[(size_t)u * 64 + lane];
    float4 mu_v = rv[lane], s_v = rv[64 + lane], e_v = epse[(size_t)v * 64 + lane];
    float ax = fmaf(fabsf(s_u.x), e_u.x, mu_u.x), bx = fmaf(fabsf(s_v.x), e_v.x, mu_v.x);
    float ay = fmaf(fabsf(s_u.y), e_u.y, mu_u.y), by = fmaf(fabsf(s_v.y), e_v.y, mu_v.y);
    float az = fmaf(fabsf(s_u.z), e_u.z, mu_u.z), bz = fmaf(fabsf(s_v.z), e_v.z, mu_v.z);
    float aw = fmaf(fabsf(s_u.w), e_u.w, mu_u.w), bw = fmaf(fabsf(s_v.w), e_v.w, mu_v.w);
    float d = ax * bx + ay * by + az * bz + aw * bw;
    d = wred(d);
    if (lane == 0) {
        float gb = fmaf(fabsf(gbs[0]), epsg[0], gbm[0]);
        out[p] = gb + bia[u] + bia[v] + d;
    }
}

// ---------------------------------------------------------------------------
extern "C" void kernel_launch(void* const* d_in, const int* in_sizes, int n_in,
                              void* d_out, int out_size, void* d_ws, size_t ws_size,
                              hipStream_t stream)
{
    const int*   x    = (const int*)d_in[0];
    const float* bt   = (const float*)d_in[1];
    const float* et   = (const float*)d_in[2];
    const float* gbm  = (const float*)d_in[3];
    const float* gbs  = (const float*)d_in[4];
    const int*   nb   = (const int*)d_in[5];
    const float* epsb = (const float*)d_in[6];
    const float* epse = (const float*)d_in[7];
    const float* epsg = (const float*)d_in[8];
    float* out = (float*)d_out;   // [0..Bp) logits, [Bp] KL scalar

    char*  ws   = (char*)d_ws;
    float* hdr  = (float*)ws;                              // NSLOT x {U,I,A,B}
    float* klpe = (float*)(ws + 512);                      // NE floats
    float* bia  = (float*)(ws + 512 + (size_t)NEn * 4);    // NE floats
    size_t entoff = 512 + (size_t)NEn * 8;                 // 16B-aligned
    h4v* enth = nullptr;
    if (ws_size >= entoff + (size_t)NEn * 512)             // fp16 rows: 512 B each
        enth = (h4v*)(ws + entoff);

    // No memset: hdr zeroed inside k_ent (block 0); cnt eliminated entirely.

    // K1: entity reparam + KL, one-shot, one wave per row.
    k_ent<<<NEn / 4, 256, 0, stream>>>(
        (const f4v*)et, (const f4v*)epse, bt, epsb,
        gbm, gbs, enth, bia, klpe, hdr, out + Bp);

    // K2: batch partials (PB blocks) || logits (Bp/8 blocks, R4 shape).
    if (enth) {
        k_log<<<PB + Bp / 8, 256, 0, stream>>>(
            (const int2*)x, (const h8v*)enth, bia, klpe, nb,
            gbm, gbs, epsg, hdr, out);
    } else {
        k_log<<<PB, 256, 0, stream>>>(         // partials only
            (const int2*)x, nullptr, bia, klpe, nb,
            gbm, gbs, epsg, hdr, out);
        k_logits_rc<<<Bp / 4, 256, 0, stream>>>(x, (const float4*)et,
                                                (const float4*)epse, bia,
                                                gbm, gbs, epsg, out);
    }

    // K3: finalize KL scalar.
    k_fin<<<1, 64, 0, stream>>>(hdr, out + Bp);
}